// Round 8
// baseline (313.119 us; speedup 1.0000x reference)
//
#include <hip/hip_runtime.h>
#include <cstdint>
#include <cstddef>

typedef unsigned short u16;
typedef __bf16 bf16x8 __attribute__((ext_vector_type(8)));
typedef float  f32x4  __attribute__((ext_vector_type(4)));
typedef u16    u16x8v __attribute__((ext_vector_type(8)));
typedef u16    u16x4  __attribute__((ext_vector_type(4)));

#define EPS 1e-6f

// ---------- helpers ----------
__device__ __forceinline__ u16 f2bf(float f) {
  union { float f; unsigned int u; } v; v.f = f;
  unsigned int u = v.u + 0x7FFFu + ((v.u >> 16) & 1u);   // RNE
  return (u16)(u >> 16);
}
__device__ __forceinline__ float bf2f(u16 h) {
  union { unsigned int u; float f; } v; v.u = ((unsigned int)h) << 16;
  return v.f;
}
__device__ __forceinline__ void async16(const void* g, void* l) {
  __builtin_amdgcn_global_load_lds(
      (const __attribute__((address_space(1))) void*)g,
      (__attribute__((address_space(3))) void*)l, 16, 0, 0);
}

// ---------- fused fp32 -> bf16 conversion (x + 4 weights, one launch) ----------
__global__ __launch_bounds__(256) void cvt_all_kernel(
    const float* __restrict__ x,
    const float* __restrict__ w0, const float* __restrict__ w1,
    const float* __restrict__ w2, const float* __restrict__ w3,
    u16* __restrict__ xb, u16* __restrict__ o0, u16* __restrict__ o1,
    u16* __restrict__ o2, u16* __restrict__ o3) {
  const int gb = blockIdx.x;
  const float* in;
  u16* out;
  int i;
  if (gb < 8192) {                       // x: 8192*256*8 = 16M elems
    in = x; out = xb; i = gb * 256 + threadIdx.x;
  } else {                               // weights: 512 blocks each
    const int wb = gb - 8192;
    in  = (wb < 512) ? w0 : (wb < 1024) ? w1 : (wb < 1536) ? w2 : w3;
    out = (wb < 512) ? o0 : (wb < 1024) ? o1 : (wb < 1536) ? o2 : o3;
    i = (wb & 511) * 256 + threadIdx.x;
  }
  const float4* p = (const float4*)in;
  float4 a = p[2 * (size_t)i], b = p[2 * (size_t)i + 1];
  u16x8v o;
  o[0] = f2bf(a.x); o[1] = f2bf(a.y); o[2] = f2bf(a.z); o[3] = f2bf(a.w);
  o[4] = f2bf(b.x); o[5] = f2bf(b.y); o[6] = f2bf(b.z); o[7] = f2bf(b.w);
  *(u16x8v*)(out + 8 * (size_t)i) = o;
}

// ---------- 256x256 8-phase Gray-code NT GEMM, single-barrier + setprio ----------
// R7 structure UNCHANGED except setprio(1)/(0) around the MFMA burst (T5:
// +21-25% measured on exactly this 8-phase counted-vmcnt structure, m218b —
// arbitration between waves staggered across the barrier window: early waves
// run MFMA while late waves drain lgkm).
// WAR: trailing lgkmcnt(0) before close barrier => reads retired before any
// wave stages over them. RAW: vmcnt(W)+barrier deadlines as enumerated R6/R7.
template <int MODE>
__global__ __launch_bounds__(512) void gemm8g(
    const u16* __restrict__ A, const u16* __restrict__ Bw,
    const float* __restrict__ bias0, const float* __restrict__ bias1,
    const float* __restrict__ bias2,
    u16* __restrict__ O0, u16* __restrict__ O1, u16* __restrict__ O2,
    float* __restrict__ Of, int K) {
  __shared__ u16 sA[2][256 * 64];
  __shared__ u16 sB[2][256 * 64];

  const int tid = threadIdx.x, wave = tid >> 6, lane = tid & 63;
  const int bm = blockIdx.x * 256, bn = blockIdx.y * 256;
  const int wmh = (wave >> 2) * 64;    // A within-half row base
  const int wq  = (wave & 3) * 32;     // B within-half row base
  const int l15 = lane & 15, l4 = lane >> 4, l7 = lane & 7;

  f32x4 acc[8][4] = {};

  const int trow = tid >> 3;                      // 0..63
  const int sch8 = ((tid & 7) ^ (trow & 7)) * 8;  // swizzled source chunk

#define STG_A(buf, qm, s, kt)                                                 \
  async16(A + (size_t)(bm + (s)*128 + (qm)*64 + trow) * K + (kt) + sch8,      \
          &sA[buf][(((qm)*128 + (s)*64) + wave * 8) * 64])
#define STG_B(buf, qn, s, kt)                                                 \
  async16(Bw + (size_t)(bn + ((s)*2 + (trow >> 5)) * 64 + (qn)*32 +           \
                        (trow & 31)) * K + (kt) + sch8,                       \
          &sB[buf][(((qn)*128 + (s)*64) + wave * 8) * 64])

  bf16x8 af[4][2], bq[2][2];

#define RD_A(buf, qm)                                                         \
  _Pragma("unroll") for (int m = 0; m < 4; m++)                               \
    _Pragma("unroll") for (int kk = 0; kk < 2; kk++)                          \
      af[m][kk] = *(const bf16x8*)&sA[buf][((qm)*128 + wmh + m * 16 + l15) * 64 \
                                           + ((kk * 4 + l4) ^ l7) * 8];
#define RD_B(buf, qn)                                                         \
  _Pragma("unroll") for (int f = 0; f < 2; f++)                               \
    _Pragma("unroll") for (int kk = 0; kk < 2; kk++)                          \
      bq[f][kk] = *(const bf16x8*)&sB[buf][((qn)*128 + wq + f * 16 + l15) * 64 \
                                           + ((kk * 4 + l4) ^ l7) * 8];

#define WAITV_(n) asm volatile("s_waitcnt vmcnt(" #n ")" ::: "memory")
#define WAITV(n) WAITV_(n)

  // phase close: MFMA burst (compiler interleaves the ds_reads issued above
  // into it, with fine-grained lgkm waits), prio-boosted; then ONE combined
  // wait + ONE barrier.
#define PH_(qm, qn, W)                                                        \
  __builtin_amdgcn_s_setprio(1);                                              \
  _Pragma("unroll") for (int kk = 0; kk < 2; kk++)                            \
    _Pragma("unroll") for (int m = 0; m < 4; m++)                             \
      _Pragma("unroll") for (int n = 0; n < 2; n++)                           \
        acc[(qm)*4 + m][(qn)*2 + n] = __builtin_amdgcn_mfma_f32_16x16x32_bf16(\
            af[m][kk], bq[n][kk], acc[(qm)*4 + m][(qn)*2 + n], 0, 0, 0);      \
  __builtin_amdgcn_s_setprio(0);                                              \
  asm volatile("s_waitcnt vmcnt(" #W ") lgkmcnt(0)" ::: "memory");            \
  __builtin_amdgcn_s_barrier();                                               \
  asm volatile("" ::: "memory");
#define PH(qm, qn, W) PH_(qm, qn, W)

#define ITER8(kO, kE2, kO2, FULL, W0, W1, W2, W3, W4, W5, W6, W7)             \
  RD_A(0, 0); RD_B(0, 0);                                                     \
  STG_B(1, 0, 0, kO); STG_B(1, 0, 1, kO);              /* O.B0 (deferred) */  \
  PH(0, 0, W0);                                                               \
  RD_B(0, 1);                                                                 \
  if (FULL) { STG_A(0, 0, 0, kE2); STG_A(0, 0, 1, kE2); }   /* E2.A0 */       \
  PH(0, 1, W1);                                                               \
  RD_A(0, 1);                                                                 \
  if (FULL) { STG_B(0, 1, 0, kE2); STG_B(0, 1, 1, kE2); }   /* E2.B1 */       \
  PH(1, 1, W2);                                                               \
  RD_B(0, 0);                                                                 \
  if (FULL) { STG_A(0, 1, 0, kE2); STG_A(0, 1, 1, kE2); }   /* E2.A1 */       \
  PH(1, 0, W3);                                                               \
  RD_A(1, 0); RD_B(1, 0);                                                     \
  if (FULL) { STG_B(0, 0, 0, kE2); STG_B(0, 0, 1, kE2); }   /* E2.B0 */       \
  PH(0, 0, W4);                                                               \
  RD_B(1, 1);                                                                 \
  if (FULL) { STG_A(1, 0, 0, kO2); STG_A(1, 0, 1, kO2); }   /* O2.A0 */       \
  PH(0, 1, W5);                                                               \
  RD_A(1, 1);                                                                 \
  if (FULL) { STG_B(1, 1, 0, kO2); STG_B(1, 1, 1, kO2); }   /* O2.B1 */       \
  PH(1, 1, W6);                                                               \
  RD_B(1, 0);                                                                 \
  if (FULL) { STG_A(1, 1, 0, kO2); STG_A(1, 1, 1, kO2); }   /* O2.A1 */       \
  PH(1, 0, W7);

  // prologue: P1=T0.A0 P2=T0.B0 P3=T0.B1 P4=T0.A1 P5=T1.A0 P6=T1.B1 P7=T1.A1
  STG_A(0, 0, 0, 0);  STG_A(0, 0, 1, 0);
  STG_B(0, 0, 0, 0);  STG_B(0, 0, 1, 0);
  STG_B(0, 1, 0, 0);  STG_B(0, 1, 1, 0);
  STG_A(0, 1, 0, 0);  STG_A(0, 1, 1, 0);
  STG_A(1, 0, 0, 64); STG_A(1, 0, 1, 64);
  STG_B(1, 1, 0, 64); STG_B(1, 1, 1, 64);
  STG_A(1, 1, 0, 64); STG_A(1, 1, 1, 64);
  WAITV(10);
  __builtin_amdgcn_s_barrier();
  asm volatile("" ::: "memory");

  const int NT = K >> 6;      // 16 K-tiles
  const int NI = NT >> 1;     // 8 iters, 2 tiles each
  // iter 0 peel: W(pE0)=10 retires T0.B1 before pE1's read; W(pE1)=10 -> T0.A1
  ITER8(64, 128, 192, true, 10, 10, 12, 6, 12, 12, 12, 6);
  for (int i = 1; i < NI - 1; ++i) {
    const int kO  = (2 * i + 1) * 64;
    const int kE2 = (2 * i + 2) * 64;
    const int kO2 = (2 * i + 3) * 64;
    ITER8(kO, kE2, kO2, true, 12, 12, 12, 6, 12, 12, 12, 6);
  }
  // tail: only O.B0 staged at pE0 (read pO0 -> W(pE3)=0)
  ITER8((NT - 1) * 64, 0, 0, false, 12, 12, 12, 0, 0, 0, 0, 0);
#undef STG_A
#undef STG_B
#undef RD_A
#undef RD_B
#undef WAITV
#undef WAITV_
#undef PH
#undef PH_
#undef ITER8

  // epilogue. C/D layout: col=lane&15, row=(lane>>4)*4+j (verified).
  const int wm = wmh * 2;
  const int wn = (wave & 3) * 64;
  const int r0 = l4 * 4, cc = l15;
  if constexpr (MODE == 1) {
    const int mat = blockIdx.y >> 2;                    // 0=Q 1=K 2=V
    u16* outp = (mat == 0) ? O0 : (mat == 1) ? O1 : O2;
    const float* bias = (mat == 0) ? bias0 : (mat == 1) ? bias1 : bias2;
    const int act = (mat < 2);
    const int colb = (blockIdx.y & 3) * 256;
    float bvv[4];
#pragma unroll
    for (int ni = 0; ni < 4; ni++) bvv[ni] = bias[colb + wn + ni * 16 + cc];
#pragma unroll
    for (int mi = 0; mi < 8; mi++) {
#pragma unroll
      for (int j = 0; j < 4; j++) {
        const int row = bm + wm + mi * 16 + r0 + j;
#pragma unroll
        for (int ni = 0; ni < 4; ni++) {               // ni inner: line-merge
          const int col = colb + wn + ni * 16 + cc;
          float val = acc[mi][ni][j] + bvv[ni];
          if (act) val = (val > 0.f) ? (val + 1.f) : __expf(val);  // phi
          outp[(size_t)row * 1024 + col] = f2bf(val);
        }
      }
    }
  } else {
    float bvv[4];
#pragma unroll
    for (int ni = 0; ni < 4; ni++) bvv[ni] = bias0[bn + wn + ni * 16 + cc];
#pragma unroll
    for (int mi = 0; mi < 8; mi++) {
#pragma unroll
      for (int j = 0; j < 4; j++) {
        const int row = bm + wm + mi * 16 + r0 + j;
#pragma unroll
        for (int ni = 0; ni < 4; ni++) {
          const int col = bn + wn + ni * 16 + cc;
          Of[(size_t)row * 1024 + col] = acc[mi][ni][j] + bvv[ni];
        }
      }
    }
  }
}

// ---------- kv partials via MFMA (NO atomics): per (chunk,bh) block ----------
__global__ __launch_bounds__(256) void kv_mfma_kernel(
    const u16* __restrict__ Kb, const u16* __restrict__ Vb,
    float* __restrict__ kv_part, float* __restrict__ ksum_part) {
  const int bh = blockIdx.y;
  const int chunk = blockIdx.x;
  const int b = bh >> 4, h = bh & 15;
  const int tid = threadIdx.x, wave = tid >> 6, lane = tid & 63;

  __shared__ u16 sKT[64 * 64];
  __shared__ u16 sVT[64 * 64];

  f32x4 acc[4] = {};
  f32x4 accs[4] = {};

  union { u16x8v u; bf16x8 b; } uo;
#pragma unroll
  for (int e = 0; e < 8; e++) uo.u[e] = 0x3F80;
  const bf16x8 ones = uo.b;

  const int half = tid >> 7;
  const int j    = tid & 127;
  const int tg   = j >> 3;
  const int dg   = j & 7;
  const u16* src = half ? Vb : Kb;
  u16* dst = half ? sVT : sKT;
  const int colb = (4 * tg + 8 * dg) & 63;

  const size_t rowBase = (size_t)b * 4096 + (size_t)chunk * 512;
  const size_t gbase = (rowBase + 4 * tg) * 1024 + (size_t)h * 64 + dg * 8;

  u16x8v pre[2][4];
#pragma unroll
  for (int s = 0; s < 4; s++)
    pre[0][s] = *(const u16x8v*)(src + gbase + (size_t)s * 1024);

#pragma unroll
  for (int st = 0; st < 8; st++) {
    const int cb = st & 1;
    __syncthreads();
#pragma unroll
    for (int e = 0; e < 8; e++) {
      u16x4 w;
      w[0] = pre[cb][0][e]; w[1] = pre[cb][1][e];
      w[2] = pre[cb][2][e]; w[3] = pre[cb][3][e];
      *(u16x4*)&dst[(dg * 8 + e) * 64 + colb] = w;
    }
    if (st + 1 < 8) {
      const size_t nb = gbase + (size_t)(st + 1) * 64 * 1024;
#pragma unroll
      for (int s = 0; s < 4; s++)
        pre[cb ^ 1][s] = *(const u16x8v*)(src + nb + (size_t)s * 1024);
    }
    __syncthreads();

#pragma unroll
    for (int kst = 0; kst < 2; kst++) {
      const int q8 = kst * 32 + (lane >> 4) * 8;
      bf16x8 bfrag;
      {
        const int rr = wave * 16 + (lane & 15);
        const int c = (q8 + 8 * (rr >> 3)) & 63;
        bfrag = *(const bf16x8*)&sVT[rr * 64 + c];
      }
#pragma unroll
      for (int i = 0; i < 4; i++) {
        const int rr = i * 16 + (lane & 15);
        const int c = (q8 + 8 * (rr >> 3)) & 63;
        const bf16x8 afrag = *(const bf16x8*)&sKT[rr * 64 + c];
        acc[i] = __builtin_amdgcn_mfma_f32_16x16x32_bf16(afrag, bfrag, acc[i], 0, 0, 0);
        if (wave == 0)
          accs[i] = __builtin_amdgcn_mfma_f32_16x16x32_bf16(afrag, ones, accs[i], 0, 0, 0);
      }
    }
  }

  const int r0 = (lane >> 4) * 4, cc = lane & 15;
  float* kvp = kv_part + ((size_t)chunk * 64 + bh) * 4096;
#pragma unroll
  for (int i = 0; i < 4; i++)
#pragma unroll
    for (int jj = 0; jj < 4; jj++)
      kvp[(size_t)(i * 16 + r0 + jj) * 64 + wave * 16 + cc] = acc[i][jj];
  if (wave == 0 && cc == 0) {
#pragma unroll
    for (int i = 0; i < 4; i++)
#pragma unroll
      for (int jj = 0; jj < 4; jj++)
        ksum_part[((size_t)chunk * 64 + bh) * 64 + i * 16 + r0 + jj] = accs[i][jj];
  }
}

// ---------- reduce 8 kv partials -> bf16 kv [bh][d][m], fp32 ksum ----------
__global__ __launch_bounds__(256) void kv_reduce_kernel(
    const float* __restrict__ kv_part, const float* __restrict__ ksum_part,
    u16* __restrict__ kvbf, float* __restrict__ ksum) {
  const int bh = blockIdx.x;
  const int tid = threadIdx.x;
#pragma unroll
  for (int it = 0; it < 4; it++) {
    const int idx = it * 1024 + tid * 4;
    float4 s = {0.f, 0.f, 0.f, 0.f};
#pragma unroll
    for (int c = 0; c < 8; c++) {
      const float4 p = *(const float4*)&kv_part[((size_t)c * 64 + bh) * 4096 + idx];
      s.x += p.x; s.y += p.y; s.z += p.z; s.w += p.w;
    }
    u16x4 o;
    o[0] = f2bf(s.x); o[1] = f2bf(s.y); o[2] = f2bf(s.z); o[3] = f2bf(s.w);
    *(u16x4*)&kvbf[(size_t)bh * 4096 + idx] = o;
  }
  if (tid < 64) {
    float s = 0.f;
#pragma unroll
    for (int c = 0; c < 8; c++)
      s += ksum_part[((size_t)c * 64 + bh) * 64 + tid];
    ksum[(size_t)bh * 64 + tid] = s;
  }
}

// ---------- attn[t, h*64+m] = (Q[t,:] @ kv) * z[t], 4 row-subtiles/block ----------
#define QST 80
__global__ __launch_bounds__(256) void attn_apply_kernel(
    const u16* __restrict__ Qb, const u16* __restrict__ kvbf,
    const float* __restrict__ ksum, u16* __restrict__ attn) {
  const int bh = blockIdx.y;
  const int t4 = blockIdx.x;           // 16 blocks x 256 rows
  const int b = bh >> 4, h = bh & 15;
  const int tid = threadIdx.x, wave = tid >> 6, lane = tid & 63;

  __shared__ u16 skvT[64 * QST];   // [m][d]  (staged ONCE per block)
  __shared__ u16 sq[64 * QST];     // [t][d]  (per sub-tile)
  __shared__ float sz[64];
  __shared__ float sks[64];
  __shared__ float szp[256];

  if (tid < 64) sks[tid] = ksum[(size_t)bh * 64 + tid] + EPS;
  const u16* kvp = kvbf + (size_t)bh * 4096;
  for (int i = tid; i < 4096; i += 256) {
    const int dd = i >> 6, mm = i & 63;
    skvT[mm * QST + dd] = kvp[i];
  }

  const size_t qbase0 = ((size_t)b * 4096 + (size_t)t4 * 256) * 1024 + h * 64;

  for (int st = 0; st < 4; ++st) {
    const size_t qbase = qbase0 + (size_t)st * 64 * 1024;
    __syncthreads();   // st=0: skvT/sks ready; st>0: prev sq reads retired (WAR)
    for (int i = tid; i < 4096; i += 256) {
      const int r = i >> 6, dd = i & 63;
      sq[r * QST + dd] = Qb[qbase + (size_t)r * 1024 + dd];
    }
    __syncthreads();

    // parallel z: 64 rows x 4 groups of 16-d partials, LDS reduce
    {
      const int zr = tid & 63, zg = tid >> 6;
      float pz = 0.f;
#pragma unroll
      for (int jj = 0; jj < 16; jj++) {
        const int dd = zg * 16 + jj;
        pz += bf2f(sq[zr * QST + dd]) * sks[dd];
      }
      szp[zg * 64 + zr] = pz;
    }
    __syncthreads();
    if (tid < 64)
      sz[tid] = 1.f / (szp[tid] + szp[64 + tid] + szp[128 + tid] + szp[192 + tid] + EPS);
    __syncthreads();

    f32x4 acc[4] = {};
#pragma unroll
    for (int ks2 = 0; ks2 < 2; ks2++) {
      const bf16x8 a = *(const bf16x8*)&sq[(wave * 16 + (lane & 15)) * QST + ks2 * 32 + (lane >> 4) * 8];
#pragma unroll
      for (int ni = 0; ni < 4; ni++) {
        const bf16x8 bv = *(const bf16x8*)&skvT[(ni * 16 + (lane & 15)) * QST + ks2 * 32 + (lane >> 4) * 8];
        acc[ni] = __builtin_amdgcn_mfma_f32_16x16x32_bf16(a, bv, acc[ni], 0, 0, 0);
      }
    }

    const int r0 = (lane >> 4) * 4, cc = lane & 15;
#pragma unroll
    for (int ni = 0; ni < 4; ni++) {
#pragma unroll
      for (int j = 0; j < 4; j++) {
        const int r = wave * 16 + r0 + j;
        const int c = ni * 16 + cc;
        const float val = acc[ni][j] * sz[r];
        attn[qbase + (size_t)r * 1024 + c] = f2bf(val);
      }
    }
  }
}

// ---------- launch ----------
extern "C" void kernel_launch(void* const* d_in, const int* in_sizes, int n_in,
                              void* d_out, int out_size, void* d_ws, size_t ws_size,
                              hipStream_t stream) {
  (void)in_sizes; (void)n_in; (void)out_size; (void)ws_size;
  const float* x  = (const float*)d_in[0];
  const float* Wq = (const float*)d_in[1];
  const float* bq = (const float*)d_in[2];
  const float* Wk = (const float*)d_in[3];
  const float* bk = (const float*)d_in[4];
  const float* Wv = (const float*)d_in[5];
  const float* bv = (const float*)d_in[6];
  const float* Wo = (const float*)d_in[7];
  const float* bo = (const float*)d_in[8];

  // B=4, T=4096, D=1024, H=16, DK=64; M = B*T = 16384
  char* ws = (char*)d_ws;
  u16* xb    = (u16*)ws;  ws += 33554432;              // [16384,1024] bf16
  u16* wqkvb = (u16*)ws;  ws += 6291456;               // [3072,1024] bf16 (Q|K|V)
  u16* wob   = (u16*)ws;  ws += 2097152;
  u16* Vb    = (u16*)ws;  ws += 33554432;
  u16* attn  = (u16*)ws;  ws += 33554432;
  float* kv_part   = (float*)ws; ws += 8388608;        // [8][64][64][64] fp32
  float* ksum_part = (float*)ws; ws += 131072;         // [8][64][64] fp32
  u16*   kvbf      = (u16*)ws;   ws += 524288;         // [64][64][64] bf16
  float* ksum      = (float*)ws; ws += 16384;          // [64][64] fp32

  u16* Qb = (u16*)d_out;
  u16* Kb = Qb + 16777216;

  cvt_all_kernel<<<10240, 256, 0, stream>>>(x, Wq, Wk, Wv, Wo,
                                            xb, wqkvb, wqkvb + 1048576,
                                            wqkvb + 2097152, wob);

  // fused QKV GEMM: [16384,1024] x [3072,1024]^T, N=3072
  gemm8g<1><<<dim3(64, 12), 512, 0, stream>>>(
      xb, wqkvb, bq, bk, bv, Qb, Kb, Vb, nullptr, 1024);

  kv_mfma_kernel<<<dim3(8, 64), dim3(256), 0, stream>>>(Kb, Vb, kv_part, ksum_part);
  kv_reduce_kernel<<<64, 256, 0, stream>>>(kv_part, ksum_part, kvbf, ksum);
  attn_apply_kernel<<<dim3(16, 64), dim3(256), 0, stream>>>(Qb, kvbf, ksum, attn);

  // output GEMM: [16384,1024] x [1024,1024]^T -> fp32
  gemm8g<0><<<dim3(64, 4), 512, 0, stream>>>(
      attn, wob, bo, nullptr, nullptr, nullptr, nullptr, nullptr,
      (float*)d_out, 1024);
}

// Round 9
// 295.723 us; speedup vs baseline: 1.0588x; 1.0588x over previous
//
#include <hip/hip_runtime.h>
#include <cstdint>
#include <cstddef>

typedef unsigned short u16;
typedef __bf16 bf16x8 __attribute__((ext_vector_type(8)));
typedef float  f32x4  __attribute__((ext_vector_type(4)));
typedef u16    u16x8v __attribute__((ext_vector_type(8)));
typedef u16    u16x4  __attribute__((ext_vector_type(4)));

#define EPS 1e-6f

// ---------- helpers ----------
__device__ __forceinline__ u16 f2bf(float f) {
  union { float f; unsigned int u; } v; v.f = f;
  unsigned int u = v.u + 0x7FFFu + ((v.u >> 16) & 1u);   // RNE
  return (u16)(u >> 16);
}
__device__ __forceinline__ float bf2f(u16 h) {
  union { unsigned int u; float f; } v; v.u = ((unsigned int)h) << 16;
  return v.f;
}
__device__ __forceinline__ void async16(const void* g, void* l) {
  __builtin_amdgcn_global_load_lds(
      (const __attribute__((address_space(1))) void*)g,
      (__attribute__((address_space(3))) void*)l, 16, 0, 0);
}

// ---------- fused fp32 -> bf16 conversion (x + 4 weights, one launch) ----------
__global__ __launch_bounds__(256) void cvt_all_kernel(
    const float* __restrict__ x,
    const float* __restrict__ w0, const float* __restrict__ w1,
    const float* __restrict__ w2, const float* __restrict__ w3,
    u16* __restrict__ xb, u16* __restrict__ o0, u16* __restrict__ o1,
    u16* __restrict__ o2, u16* __restrict__ o3) {
  const int gb = blockIdx.x;
  const float* in;
  u16* out;
  int i;
  if (gb < 8192) {                       // x: 8192*256*8 = 16M elems
    in = x; out = xb; i = gb * 256 + threadIdx.x;
  } else {                               // weights: 512 blocks each
    const int wb = gb - 8192;
    in  = (wb < 512) ? w0 : (wb < 1024) ? w1 : (wb < 1536) ? w2 : w3;
    out = (wb < 512) ? o0 : (wb < 1024) ? o1 : (wb < 1536) ? o2 : o3;
    i = (wb & 511) * 256 + threadIdx.x;
  }
  const float4* p = (const float4*)in;
  float4 a = p[2 * (size_t)i], b = p[2 * (size_t)i + 1];
  u16x8v o;
  o[0] = f2bf(a.x); o[1] = f2bf(a.y); o[2] = f2bf(a.z); o[3] = f2bf(a.w);
  o[4] = f2bf(b.x); o[5] = f2bf(b.y); o[6] = f2bf(b.z); o[7] = f2bf(b.w);
  *(u16x8v*)(out + 8 * (size_t)i) = o;
}

// ---------- 256x256 4-phase NT GEMM, relaxed single-barrier phases ----------
// Composition of two harness-verified pieces:
//  - R4's stage layout / waits (full-B in regs bq[4][2], A in halves; 24
//    LDS reads/tile = minimum; steady waits (8,8,8,8), prologue vmcnt(6),
//    peel (8,2,0,0) — deadline enumeration unchanged by barrier coarsening
//    since (issue, wait, barrier, read) ORDER is preserved).
//  - R7's relaxed close {MFMA burst; s_waitcnt vmcnt(W) lgkmcnt(0);
//    s_barrier} — compiler interleaves ds_reads into the burst with
//    fine-grained lgkm waits; trailing lgkmcnt(0)+barrier is the WAR fence
//    (every staged region's last reader retires >=1 close earlier; all 8
//    stage/read pairs re-checked at this granularity).
// NO setprio: R8 measured it at -12% on the relaxed structure (it
// deprioritizes the waves issuing the reads the burst depends on).
// 32 barriers/block (vs R7's 64) and 32-MFMA bursts for latency hiding.
template <int MODE>
__global__ __launch_bounds__(512) void gemm4r(
    const u16* __restrict__ A, const u16* __restrict__ Bw,
    const float* __restrict__ bias0, const float* __restrict__ bias1,
    const float* __restrict__ bias2,
    u16* __restrict__ O0, u16* __restrict__ O1, u16* __restrict__ O2,
    float* __restrict__ Of, int K) {
  __shared__ u16 sA[2][256 * 64];
  __shared__ u16 sB[2][256 * 64];

  const int tid = threadIdx.x, wave = tid >> 6, lane = tid & 63;
  const int bm = blockIdx.x * 256, bn = blockIdx.y * 256;
  const int wmh = (wave >> 2) * 64;    // A within-half row base
  const int wq  = (wave & 3) * 32;     // B within-half row base
  const int l15 = lane & 15, l4 = lane >> 4, l7 = lane & 7;

  f32x4 acc[8][4] = {};

  const int trow = tid >> 3;                      // 0..63
  const int sch8 = ((tid & 7) ^ (trow & 7)) * 8;  // swizzled source chunk

  // A-half(qm) region s: LDS rows qm*128+s*64+trow <-> global row
  //   bm + s*128 + qm*64 + trow.        (verified R3-R8)
#define STG_A(buf, qm, s, kt)                                                 \
  async16(A + (size_t)(bm + (s)*128 + (qm)*64 + trow) * K + (kt) + sch8,      \
          &sA[buf][(((qm)*128 + (s)*64) + wave * 8) * 64])
  // B-half(qn) region s: LDS rows qn*128+s*64+trow <-> global row
  //   bn + (s*2 + (trow>>5))*64 + qn*32 + (trow&31).   (verified R3-R8)
#define STG_B(buf, qn, s, kt)                                                 \
  async16(Bw + (size_t)(bn + ((s)*2 + (trow >> 5)) * 64 + (qn)*32 +           \
                        (trow & 31)) * K + (kt) + sch8,                       \
          &sB[buf][(((qn)*128 + (s)*64) + wave * 8) * 64])

  bf16x8 af[4][2], bq[4][2];

#define RD_A(buf, qm)                                                         \
  _Pragma("unroll") for (int m = 0; m < 4; m++)                               \
    _Pragma("unroll") for (int kk = 0; kk < 2; kk++)                          \
      af[m][kk] = *(const bf16x8*)&sA[buf][((qm)*128 + wmh + m * 16 + l15) * 64 \
                                           + ((kk * 4 + l4) ^ l7) * 8];
  // bq[nf] -> output col wn + nf*16; row = (nf>>1)*128 + wq + (nf&1)*16 + l15
  // (inverse of STG_B's mapping; verified R4)
#define RD_B(buf)                                                             \
  _Pragma("unroll") for (int nf = 0; nf < 4; nf++)                            \
    _Pragma("unroll") for (int kk = 0; kk < 2; kk++)                          \
      bq[nf][kk] = *(const bf16x8*)&sB[buf][((nf >> 1) * 128 + wq +           \
                                            (nf & 1) * 16 + l15) * 64 +       \
                                           ((kk * 4 + l4) ^ l7) * 8];

#define WAITV_(n) asm volatile("s_waitcnt vmcnt(" #n ")" ::: "memory")
#define WAITV(n) WAITV_(n)

  // relaxed phase close: 32-MFMA burst (compiler interleaves the ds_reads
  // issued above into it), then ONE combined wait + ONE barrier.
#define PH_EXEC_(qm, W)                                                       \
  _Pragma("unroll") for (int kk = 0; kk < 2; kk++)                            \
    _Pragma("unroll") for (int m = 0; m < 4; m++)                             \
      _Pragma("unroll") for (int nf = 0; nf < 4; nf++)                        \
        acc[(qm)*4 + m][nf] = __builtin_amdgcn_mfma_f32_16x16x32_bf16(        \
            af[m][kk], bq[nf][kk], acc[(qm)*4 + m][nf], 0, 0, 0);             \
  asm volatile("s_waitcnt vmcnt(" #W ") lgkmcnt(0)" ::: "memory");            \
  __builtin_amdgcn_s_barrier();                                               \
  asm volatile("" ::: "memory");
#define PH_EXEC(qm, W) PH_EXEC_(qm, W)

#define ITER_BODY(kO, kE2, kO2, hasT2, hasT3, W0, W1, W2, W3)                 \
  /* p0: T0 (buf0) B-full + A-half0; stage T1.A1 (deferred) */                \
  RD_B(0); RD_A(0, 0);                                                        \
  STG_A(1, 1, 0, kO); STG_A(1, 1, 1, kO);                                     \
  PH_EXEC(0, W0);                                                             \
  /* p1: T0 A-half1; stage T2.B + T2.A0 */                                    \
  RD_A(0, 1);                                                                 \
  if (hasT2) {                                                                \
    STG_B(0, 0, 0, kE2); STG_B(0, 0, 1, kE2);                                 \
    STG_B(0, 1, 0, kE2); STG_B(0, 1, 1, kE2);                                 \
    STG_A(0, 0, 0, kE2); STG_A(0, 0, 1, kE2);                                 \
  }                                                                           \
  PH_EXEC(1, W1);                                                             \
  /* p2: T1 (buf1) B-full + A-half0; stage T2.A1 */                           \
  RD_B(1); RD_A(1, 0);                                                        \
  if (hasT2) { STG_A(0, 1, 0, kE2); STG_A(0, 1, 1, kE2); }                    \
  PH_EXEC(0, W2);                                                             \
  /* p3: T1 A-half1; stage T3.B + T3.A0 */                                    \
  RD_A(1, 1);                                                                 \
  if (hasT3) {                                                                \
    STG_B(1, 0, 0, kO2); STG_B(1, 0, 1, kO2);                                 \
    STG_B(1, 1, 0, kO2); STG_B(1, 1, 1, kO2);                                 \
    STG_A(1, 0, 0, kO2); STG_A(1, 0, 1, kO2);                                 \
  }                                                                           \
  PH_EXEC(1, W3);

  // prologue: T0 full (B,A0,A1) + T1 (B,A0); T1.A1 deferred to iter-0 p0.
  STG_B(0, 0, 0, 0);  STG_B(0, 0, 1, 0);  STG_B(0, 1, 0, 0);  STG_B(0, 1, 1, 0);
  STG_A(0, 0, 0, 0);  STG_A(0, 0, 1, 0);
  STG_A(0, 1, 0, 0);  STG_A(0, 1, 1, 0);
  STG_B(1, 0, 0, 64); STG_B(1, 0, 1, 64); STG_B(1, 1, 0, 64); STG_B(1, 1, 1, 64);
  STG_A(1, 0, 0, 64); STG_A(1, 0, 1, 64);
  WAITV(6);                               // T0's 8 loads retired
  __builtin_amdgcn_s_barrier();
  asm volatile("" ::: "memory");

  const int NT = K >> 6;      // K-tiles of 64
  const int NI = NT >> 1;     // 2 tiles / iter (NT even)
  for (int i = 0; i < NI - 1; ++i) {
    const int kO  = (2 * i + 1) * 64;
    const int kE2 = (2 * i + 2) * 64;
    const int kO2 = (2 * i + 3) * 64;
    ITER_BODY(kO, kE2, kO2, true, true, 8, 8, 8, 8);
  }
  {  // peeled last iteration (no T2/T3)
    const int kO = (NT - 1) * 64;
    ITER_BODY(kO, 0, 0, false, false, 8, 2, 0, 0);
  }
#undef STG_A
#undef STG_B
#undef RD_A
#undef RD_B
#undef WAITV
#undef WAITV_
#undef PH_EXEC
#undef PH_EXEC_
#undef ITER_BODY

  // epilogue. C/D layout: col=lane&15, row=(lane>>4)*4+j (verified).
  const int wm = wmh * 2;
  const int wn = (wave & 3) * 64;
  const int r0 = l4 * 4, cc = l15;
  if constexpr (MODE == 1) {
    const int mat = blockIdx.y >> 2;                    // 0=Q 1=K 2=V
    u16* outp = (mat == 0) ? O0 : (mat == 1) ? O1 : O2;
    const float* bias = (mat == 0) ? bias0 : (mat == 1) ? bias1 : bias2;
    const int act = (mat < 2);
    const int colb = (blockIdx.y & 3) * 256;
    float bvv[4];
#pragma unroll
    for (int ni = 0; ni < 4; ni++) bvv[ni] = bias[colb + wn + ni * 16 + cc];
#pragma unroll
    for (int mi = 0; mi < 8; mi++) {
#pragma unroll
      for (int j = 0; j < 4; j++) {
        const int row = bm + wm + mi * 16 + r0 + j;
#pragma unroll
        for (int ni = 0; ni < 4; ni++) {               // ni inner: line-merge
          const int col = colb + wn + ni * 16 + cc;
          float val = acc[mi][ni][j] + bvv[ni];
          if (act) val = (val > 0.f) ? (val + 1.f) : __expf(val);  // phi
          outp[(size_t)row * 1024 + col] = f2bf(val);
        }
      }
    }
  } else {
    float bvv[4];
#pragma unroll
    for (int ni = 0; ni < 4; ni++) bvv[ni] = bias0[bn + wn + ni * 16 + cc];
#pragma unroll
    for (int mi = 0; mi < 8; mi++) {
#pragma unroll
      for (int j = 0; j < 4; j++) {
        const int row = bm + wm + mi * 16 + r0 + j;
#pragma unroll
        for (int ni = 0; ni < 4; ni++) {
          const int col = bn + wn + ni * 16 + cc;
          Of[(size_t)row * 1024 + col] = acc[mi][ni][j] + bvv[ni];
        }
      }
    }
  }
}

// ---------- kv partials via MFMA (NO atomics): per (chunk,bh) block ----------
__global__ __launch_bounds__(256) void kv_mfma_kernel(
    const u16* __restrict__ Kb, const u16* __restrict__ Vb,
    float* __restrict__ kv_part, float* __restrict__ ksum_part) {
  const int bh = blockIdx.y;
  const int chunk = blockIdx.x;
  const int b = bh >> 4, h = bh & 15;
  const int tid = threadIdx.x, wave = tid >> 6, lane = tid & 63;

  __shared__ u16 sKT[64 * 64];
  __shared__ u16 sVT[64 * 64];

  f32x4 acc[4] = {};
  f32x4 accs[4] = {};

  union { u16x8v u; bf16x8 b; } uo;
#pragma unroll
  for (int e = 0; e < 8; e++) uo.u[e] = 0x3F80;
  const bf16x8 ones = uo.b;

  const int half = tid >> 7;
  const int j    = tid & 127;
  const int tg   = j >> 3;
  const int dg   = j & 7;
  const u16* src = half ? Vb : Kb;
  u16* dst = half ? sVT : sKT;
  const int colb = (4 * tg + 8 * dg) & 63;

  const size_t rowBase = (size_t)b * 4096 + (size_t)chunk * 512;
  const size_t gbase = (rowBase + 4 * tg) * 1024 + (size_t)h * 64 + dg * 8;

  u16x8v pre[2][4];
#pragma unroll
  for (int s = 0; s < 4; s++)
    pre[0][s] = *(const u16x8v*)(src + gbase + (size_t)s * 1024);

#pragma unroll
  for (int st = 0; st < 8; st++) {
    const int cb = st & 1;
    __syncthreads();
#pragma unroll
    for (int e = 0; e < 8; e++) {
      u16x4 w;
      w[0] = pre[cb][0][e]; w[1] = pre[cb][1][e];
      w[2] = pre[cb][2][e]; w[3] = pre[cb][3][e];
      *(u16x4*)&dst[(dg * 8 + e) * 64 + colb] = w;
    }
    if (st + 1 < 8) {
      const size_t nb = gbase + (size_t)(st + 1) * 64 * 1024;
#pragma unroll
      for (int s = 0; s < 4; s++)
        pre[cb ^ 1][s] = *(const u16x8v*)(src + nb + (size_t)s * 1024);
    }
    __syncthreads();

#pragma unroll
    for (int kst = 0; kst < 2; kst++) {
      const int q8 = kst * 32 + (lane >> 4) * 8;
      bf16x8 bfrag;
      {
        const int rr = wave * 16 + (lane & 15);
        const int c = (q8 + 8 * (rr >> 3)) & 63;
        bfrag = *(const bf16x8*)&sVT[rr * 64 + c];
      }
#pragma unroll
      for (int i = 0; i < 4; i++) {
        const int rr = i * 16 + (lane & 15);
        const int c = (q8 + 8 * (rr >> 3)) & 63;
        const bf16x8 afrag = *(const bf16x8*)&sKT[rr * 64 + c];
        acc[i] = __builtin_amdgcn_mfma_f32_16x16x32_bf16(afrag, bfrag, acc[i], 0, 0, 0);
        if (wave == 0)
          accs[i] = __builtin_amdgcn_mfma_f32_16x16x32_bf16(afrag, ones, accs[i], 0, 0, 0);
      }
    }
  }

  const int r0 = (lane >> 4) * 4, cc = lane & 15;
  float* kvp = kv_part + ((size_t)chunk * 64 + bh) * 4096;
#pragma unroll
  for (int i = 0; i < 4; i++)
#pragma unroll
    for (int jj = 0; jj < 4; jj++)
      kvp[(size_t)(i * 16 + r0 + jj) * 64 + wave * 16 + cc] = acc[i][jj];
  if (wave == 0 && cc == 0) {
#pragma unroll
    for (int i = 0; i < 4; i++)
#pragma unroll
      for (int jj = 0; jj < 4; jj++)
        ksum_part[((size_t)chunk * 64 + bh) * 64 + i * 16 + r0 + jj] = accs[i][jj];
  }
}

// ---------- reduce 8 kv partials -> bf16 kv [bh][d][m], fp32 ksum ----------
__global__ __launch_bounds__(256) void kv_reduce_kernel(
    const float* __restrict__ kv_part, const float* __restrict__ ksum_part,
    u16* __restrict__ kvbf, float* __restrict__ ksum) {
  const int bh = blockIdx.x;
  const int tid = threadIdx.x;
#pragma unroll
  for (int it = 0; it < 4; it++) {
    const int idx = it * 1024 + tid * 4;
    float4 s = {0.f, 0.f, 0.f, 0.f};
#pragma unroll
    for (int c = 0; c < 8; c++) {
      const float4 p = *(const float4*)&kv_part[((size_t)c * 64 + bh) * 4096 + idx];
      s.x += p.x; s.y += p.y; s.z += p.z; s.w += p.w;
    }
    u16x4 o;
    o[0] = f2bf(s.x); o[1] = f2bf(s.y); o[2] = f2bf(s.z); o[3] = f2bf(s.w);
    *(u16x4*)&kvbf[(size_t)bh * 4096 + idx] = o;
  }
  if (tid < 64) {
    float s = 0.f;
#pragma unroll
    for (int c = 0; c < 8; c++)
      s += ksum_part[((size_t)c * 64 + bh) * 64 + tid];
    ksum[(size_t)bh * 64 + tid] = s;
  }
}

// ---------- attn[t, h*64+m] = (Q[t,:] @ kv) * z[t], 4 row-subtiles/block ----------
#define QST 80
__global__ __launch_bounds__(256) void attn_apply_kernel(
    const u16* __restrict__ Qb, const u16* __restrict__ kvbf,
    const float* __restrict__ ksum, u16* __restrict__ attn) {
  const int bh = blockIdx.y;
  const int t4 = blockIdx.x;           // 16 blocks x 256 rows
  const int b = bh >> 4, h = bh & 15;
  const int tid = threadIdx.x, wave = tid >> 6, lane = tid & 63;

  __shared__ u16 skvT[64 * QST];   // [m][d]  (staged ONCE per block)
  __shared__ u16 sq[64 * QST];     // [t][d]  (per sub-tile)
  __shared__ float sz[64];
  __shared__ float sks[64];
  __shared__ float szp[256];

  if (tid < 64) sks[tid] = ksum[(size_t)bh * 64 + tid] + EPS;
  const u16* kvp = kvbf + (size_t)bh * 4096;
  for (int i = tid; i < 4096; i += 256) {
    const int dd = i >> 6, mm = i & 63;
    skvT[mm * QST + dd] = kvp[i];
  }

  const size_t qbase0 = ((size_t)b * 4096 + (size_t)t4 * 256) * 1024 + h * 64;

  for (int st = 0; st < 4; ++st) {
    const size_t qbase = qbase0 + (size_t)st * 64 * 1024;
    __syncthreads();   // st=0: skvT/sks ready; st>0: prev sq reads retired (WAR)
    for (int i = tid; i < 4096; i += 256) {
      const int r = i >> 6, dd = i & 63;
      sq[r * QST + dd] = Qb[qbase + (size_t)r * 1024 + dd];
    }
    __syncthreads();

    // parallel z: 64 rows x 4 groups of 16-d partials, LDS reduce
    {
      const int zr = tid & 63, zg = tid >> 6;
      float pz = 0.f;
#pragma unroll
      for (int jj = 0; jj < 16; jj++) {
        const int dd = zg * 16 + jj;
        pz += bf2f(sq[zr * QST + dd]) * sks[dd];
      }
      szp[zg * 64 + zr] = pz;
    }
    __syncthreads();
    if (tid < 64)
      sz[tid] = 1.f / (szp[tid] + szp[64 + tid] + szp[128 + tid] + szp[192 + tid] + EPS);
    __syncthreads();

    f32x4 acc[4] = {};
#pragma unroll
    for (int ks2 = 0; ks2 < 2; ks2++) {
      const bf16x8 a = *(const bf16x8*)&sq[(wave * 16 + (lane & 15)) * QST + ks2 * 32 + (lane >> 4) * 8];
#pragma unroll
      for (int ni = 0; ni < 4; ni++) {
        const bf16x8 bv = *(const bf16x8*)&skvT[(ni * 16 + (lane & 15)) * QST + ks2 * 32 + (lane >> 4) * 8];
        acc[ni] = __builtin_amdgcn_mfma_f32_16x16x32_bf16(a, bv, acc[ni], 0, 0, 0);
      }
    }

    const int r0 = (lane >> 4) * 4, cc = lane & 15;
#pragma unroll
    for (int ni = 0; ni < 4; ni++) {
#pragma unroll
      for (int j = 0; j < 4; j++) {
        const int r = wave * 16 + r0 + j;
        const int c = ni * 16 + cc;
        const float val = acc[ni][j] * sz[r];
        attn[qbase + (size_t)r * 1024 + c] = f2bf(val);
      }
    }
  }
}

// ---------- launch ----------
extern "C" void kernel_launch(void* const* d_in, const int* in_sizes, int n_in,
                              void* d_out, int out_size, void* d_ws, size_t ws_size,
                              hipStream_t stream) {
  (void)in_sizes; (void)n_in; (void)out_size; (void)ws_size;
  const float* x  = (const float*)d_in[0];
  const float* Wq = (const float*)d_in[1];
  const float* bq = (const float*)d_in[2];
  const float* Wk = (const float*)d_in[3];
  const float* bk = (const float*)d_in[4];
  const float* Wv = (const float*)d_in[5];
  const float* bv = (const float*)d_in[6];
  const float* Wo = (const float*)d_in[7];
  const float* bo = (const float*)d_in[8];

  // B=4, T=4096, D=1024, H=16, DK=64; M = B*T = 16384
  char* ws = (char*)d_ws;
  u16* xb    = (u16*)ws;  ws += 33554432;              // [16384,1024] bf16
  u16* wqkvb = (u16*)ws;  ws += 6291456;               // [3072,1024] bf16 (Q|K|V)
  u16* wob   = (u16*)ws;  ws += 2097152;
  u16* Vb    = (u16*)ws;  ws += 33554432;
  u16* attn  = (u16*)ws;  ws += 33554432;
  float* kv_part   = (float*)ws; ws += 8388608;        // [8][64][64][64] fp32
  float* ksum_part = (float*)ws; ws += 131072;         // [8][64][64] fp32
  u16*   kvbf      = (u16*)ws;   ws += 524288;         // [64][64][64] bf16
  float* ksum      = (float*)ws; ws += 16384;          // [64][64] fp32

  u16* Qb = (u16*)d_out;
  u16* Kb = Qb + 16777216;

  cvt_all_kernel<<<10240, 256, 0, stream>>>(x, Wq, Wk, Wv, Wo,
                                            xb, wqkvb, wqkvb + 1048576,
                                            wqkvb + 2097152, wob);

  // fused QKV GEMM: [16384,1024] x [3072,1024]^T, N=3072
  gemm4r<1><<<dim3(64, 12), 512, 0, stream>>>(
      xb, wqkvb, bq, bk, bv, Qb, Kb, Vb, nullptr, 1024);

  kv_mfma_kernel<<<dim3(8, 64), dim3(256), 0, stream>>>(Kb, Vb, kv_part, ksum_part);
  kv_reduce_kernel<<<64, 256, 0, stream>>>(kv_part, ksum_part, kvbf, ksum);
  attn_apply_kernel<<<dim3(16, 64), dim3(256), 0, stream>>>(Qb, kvbf, ksum, attn);

  // output GEMM: [16384,1024] x [1024,1024]^T -> fp32
  gemm4r<0><<<dim3(64, 4), 512, 0, stream>>>(
      attn, wob, bo, nullptr, nullptr, nullptr, nullptr, nullptr,
      (float*)d_out, 1024);
}

// Round 10
// 295.112 us; speedup vs baseline: 1.0610x; 1.0021x over previous
//
#include <hip/hip_runtime.h>
#include <cstdint>
#include <cstddef>

typedef unsigned short u16;
typedef __bf16 bf16x8 __attribute__((ext_vector_type(8)));
typedef float  f32x4  __attribute__((ext_vector_type(4)));
typedef u16    u16x8v __attribute__((ext_vector_type(8)));
typedef u16    u16x4  __attribute__((ext_vector_type(4)));

#define EPS 1e-6f

// ---------- helpers ----------
__device__ __forceinline__ u16 f2bf(float f) {
  union { float f; unsigned int u; } v; v.f = f;
  unsigned int u = v.u + 0x7FFFu + ((v.u >> 16) & 1u);   // RNE
  return (u16)(u >> 16);
}
__device__ __forceinline__ float bf2f(u16 h) {
  union { unsigned int u; float f; } v; v.u = ((unsigned int)h) << 16;
  return v.f;
}
__device__ __forceinline__ void async16(const void* g, void* l) {
  __builtin_amdgcn_global_load_lds(
      (const __attribute__((address_space(1))) void*)g,
      (__attribute__((address_space(3))) void*)l, 16, 0, 0);
}

// ---------- fused fp32 -> bf16 conversion (x + 4 weights, one launch) ----------
__global__ __launch_bounds__(256) void cvt_all_kernel(
    const float* __restrict__ x,
    const float* __restrict__ w0, const float* __restrict__ w1,
    const float* __restrict__ w2, const float* __restrict__ w3,
    u16* __restrict__ xb, u16* __restrict__ o0, u16* __restrict__ o1,
    u16* __restrict__ o2, u16* __restrict__ o3) {
  const int gb = blockIdx.x;
  const float* in;
  u16* out;
  int i;
  if (gb < 8192) {                       // x: 8192*256*8 = 16M elems
    in = x; out = xb; i = gb * 256 + threadIdx.x;
  } else {                               // weights: 512 blocks each
    const int wb = gb - 8192;
    in  = (wb < 512) ? w0 : (wb < 1024) ? w1 : (wb < 1536) ? w2 : w3;
    out = (wb < 512) ? o0 : (wb < 1024) ? o1 : (wb < 1536) ? o2 : o3;
    i = (wb & 511) * 256 + threadIdx.x;
  }
  const float4* p = (const float4*)in;
  float4 a = p[2 * (size_t)i], b = p[2 * (size_t)i + 1];
  u16x8v o;
  o[0] = f2bf(a.x); o[1] = f2bf(a.y); o[2] = f2bf(a.z); o[3] = f2bf(a.w);
  o[4] = f2bf(b.x); o[5] = f2bf(b.y); o[6] = f2bf(b.z); o[7] = f2bf(b.w);
  *(u16x8v*)(out + 8 * (size_t)i) = o;
}

// ---------- 256x256 4-phase NT GEMM, relaxed single-barrier phases ----------
// R9 known-good: UNCHANGED (105 us QKV, 44% MfmaUtil, 0 conflicts).
template <int MODE>
__global__ __launch_bounds__(512) void gemm4r(
    const u16* __restrict__ A, const u16* __restrict__ Bw,
    const float* __restrict__ bias0, const float* __restrict__ bias1,
    const float* __restrict__ bias2,
    u16* __restrict__ O0, u16* __restrict__ O1, u16* __restrict__ O2,
    float* __restrict__ Of, int K) {
  __shared__ u16 sA[2][256 * 64];
  __shared__ u16 sB[2][256 * 64];

  const int tid = threadIdx.x, wave = tid >> 6, lane = tid & 63;
  const int bm = blockIdx.x * 256, bn = blockIdx.y * 256;
  const int wmh = (wave >> 2) * 64;    // A within-half row base
  const int wq  = (wave & 3) * 32;     // B within-half row base
  const int l15 = lane & 15, l4 = lane >> 4, l7 = lane & 7;

  f32x4 acc[8][4] = {};

  const int trow = tid >> 3;                      // 0..63
  const int sch8 = ((tid & 7) ^ (trow & 7)) * 8;  // swizzled source chunk

#define STG_A(buf, qm, s, kt)                                                 \
  async16(A + (size_t)(bm + (s)*128 + (qm)*64 + trow) * K + (kt) + sch8,      \
          &sA[buf][(((qm)*128 + (s)*64) + wave * 8) * 64])
#define STG_B(buf, qn, s, kt)                                                 \
  async16(Bw + (size_t)(bn + ((s)*2 + (trow >> 5)) * 64 + (qn)*32 +           \
                        (trow & 31)) * K + (kt) + sch8,                       \
          &sB[buf][(((qn)*128 + (s)*64) + wave * 8) * 64])

  bf16x8 af[4][2], bq[4][2];

#define RD_A(buf, qm)                                                         \
  _Pragma("unroll") for (int m = 0; m < 4; m++)                               \
    _Pragma("unroll") for (int kk = 0; kk < 2; kk++)                          \
      af[m][kk] = *(const bf16x8*)&sA[buf][((qm)*128 + wmh + m * 16 + l15) * 64 \
                                           + ((kk * 4 + l4) ^ l7) * 8];
#define RD_B(buf)                                                             \
  _Pragma("unroll") for (int nf = 0; nf < 4; nf++)                            \
    _Pragma("unroll") for (int kk = 0; kk < 2; kk++)                          \
      bq[nf][kk] = *(const bf16x8*)&sB[buf][((nf >> 1) * 128 + wq +           \
                                            (nf & 1) * 16 + l15) * 64 +       \
                                           ((kk * 4 + l4) ^ l7) * 8];

#define WAITV_(n) asm volatile("s_waitcnt vmcnt(" #n ")" ::: "memory")
#define WAITV(n) WAITV_(n)

#define PH_EXEC_(qm, W)                                                       \
  _Pragma("unroll") for (int kk = 0; kk < 2; kk++)                            \
    _Pragma("unroll") for (int m = 0; m < 4; m++)                             \
      _Pragma("unroll") for (int nf = 0; nf < 4; nf++)                        \
        acc[(qm)*4 + m][nf] = __builtin_amdgcn_mfma_f32_16x16x32_bf16(        \
            af[m][kk], bq[nf][kk], acc[(qm)*4 + m][nf], 0, 0, 0);             \
  asm volatile("s_waitcnt vmcnt(" #W ") lgkmcnt(0)" ::: "memory");            \
  __builtin_amdgcn_s_barrier();                                               \
  asm volatile("" ::: "memory");
#define PH_EXEC(qm, W) PH_EXEC_(qm, W)

#define ITER_BODY(kO, kE2, kO2, hasT2, hasT3, W0, W1, W2, W3)                 \
  RD_B(0); RD_A(0, 0);                                                        \
  STG_A(1, 1, 0, kO); STG_A(1, 1, 1, kO);                                     \
  PH_EXEC(0, W0);                                                             \
  RD_A(0, 1);                                                                 \
  if (hasT2) {                                                                \
    STG_B(0, 0, 0, kE2); STG_B(0, 0, 1, kE2);                                 \
    STG_B(0, 1, 0, kE2); STG_B(0, 1, 1, kE2);                                 \
    STG_A(0, 0, 0, kE2); STG_A(0, 0, 1, kE2);                                 \
  }                                                                           \
  PH_EXEC(1, W1);                                                             \
  RD_B(1); RD_A(1, 0);                                                        \
  if (hasT2) { STG_A(0, 1, 0, kE2); STG_A(0, 1, 1, kE2); }                    \
  PH_EXEC(0, W2);                                                             \
  RD_A(1, 1);                                                                 \
  if (hasT3) {                                                                \
    STG_B(1, 0, 0, kO2); STG_B(1, 0, 1, kO2);                                 \
    STG_B(1, 1, 0, kO2); STG_B(1, 1, 1, kO2);                                 \
    STG_A(1, 0, 0, kO2); STG_A(1, 0, 1, kO2);                                 \
  }                                                                           \
  PH_EXEC(1, W3);

  // prologue: T0 full (B,A0,A1) + T1 (B,A0); T1.A1 deferred to iter-0 p0.
  STG_B(0, 0, 0, 0);  STG_B(0, 0, 1, 0);  STG_B(0, 1, 0, 0);  STG_B(0, 1, 1, 0);
  STG_A(0, 0, 0, 0);  STG_A(0, 0, 1, 0);
  STG_A(0, 1, 0, 0);  STG_A(0, 1, 1, 0);
  STG_B(1, 0, 0, 64); STG_B(1, 0, 1, 64); STG_B(1, 1, 0, 64); STG_B(1, 1, 1, 64);
  STG_A(1, 0, 0, 64); STG_A(1, 0, 1, 64);
  WAITV(6);                               // T0's 8 loads retired
  __builtin_amdgcn_s_barrier();
  asm volatile("" ::: "memory");

  const int NT = K >> 6;      // K-tiles of 64
  const int NI = NT >> 1;     // 2 tiles / iter (NT even)
  for (int i = 0; i < NI - 1; ++i) {
    const int kO  = (2 * i + 1) * 64;
    const int kE2 = (2 * i + 2) * 64;
    const int kO2 = (2 * i + 3) * 64;
    ITER_BODY(kO, kE2, kO2, true, true, 8, 8, 8, 8);
  }
  {  // peeled last iteration (no T2/T3)
    const int kO = (NT - 1) * 64;
    ITER_BODY(kO, 0, 0, false, false, 8, 2, 0, 0);
  }
#undef STG_A
#undef STG_B
#undef RD_A
#undef RD_B
#undef WAITV
#undef WAITV_
#undef PH_EXEC
#undef PH_EXEC_
#undef ITER_BODY

  // epilogue. C/D layout: col=lane&15, row=(lane>>4)*4+j (verified).
  const int wm = wmh * 2;
  const int wn = (wave & 3) * 64;
  const int r0 = l4 * 4, cc = l15;
  if constexpr (MODE == 1) {
    const int mat = blockIdx.y >> 2;                    // 0=Q 1=K 2=V
    u16* outp = (mat == 0) ? O0 : (mat == 1) ? O1 : O2;
    const float* bias = (mat == 0) ? bias0 : (mat == 1) ? bias1 : bias2;
    const int act = (mat < 2);
    const int colb = (blockIdx.y & 3) * 256;
    float bvv[4];
#pragma unroll
    for (int ni = 0; ni < 4; ni++) bvv[ni] = bias[colb + wn + ni * 16 + cc];
#pragma unroll
    for (int mi = 0; mi < 8; mi++) {
#pragma unroll
      for (int j = 0; j < 4; j++) {
        const int row = bm + wm + mi * 16 + r0 + j;
#pragma unroll
        for (int ni = 0; ni < 4; ni++) {               // ni inner: line-merge
          const int col = colb + wn + ni * 16 + cc;
          float val = acc[mi][ni][j] + bvv[ni];
          if (act) val = (val > 0.f) ? (val + 1.f) : __expf(val);  // phi
          outp[(size_t)row * 1024 + col] = f2bf(val);
        }
      }
    }
  } else {
    float bvv[4];
#pragma unroll
    for (int ni = 0; ni < 4; ni++) bvv[ni] = bias0[bn + wn + ni * 16 + cc];
#pragma unroll
    for (int mi = 0; mi < 8; mi++) {
#pragma unroll
      for (int j = 0; j < 4; j++) {
        const int row = bm + wm + mi * 16 + r0 + j;
#pragma unroll
        for (int ni = 0; ni < 4; ni++) {
          const int col = bn + wn + ni * 16 + cc;
          Of[(size_t)row * 1024 + col] = acc[mi][ni][j] + bvv[ni];
        }
      }
    }
  }
}

// ---------- kv partials via MFMA: 16 chunks of 256 t (2x TLP vs R9) ----------
// Block (chunk,bh): 4 stages of 64 t; plain stores to kv_part (aliased onto
// the attn buffer — dead before attn_apply writes it, stream-ordered).
__global__ __launch_bounds__(256) void kv_mfma_kernel(
    const u16* __restrict__ Kb, const u16* __restrict__ Vb,
    float* __restrict__ kv_part, float* __restrict__ ksum_part) {
  const int bh = blockIdx.y;
  const int chunk = blockIdx.x;
  const int b = bh >> 4, h = bh & 15;
  const int tid = threadIdx.x, wave = tid >> 6, lane = tid & 63;

  __shared__ u16 sKT[64 * 64];
  __shared__ u16 sVT[64 * 64];

  f32x4 acc[4] = {};
  f32x4 accs[4] = {};

  union { u16x8v u; bf16x8 b; } uo;
#pragma unroll
  for (int e = 0; e < 8; e++) uo.u[e] = 0x3F80;
  const bf16x8 ones = uo.b;

  const int half = tid >> 7;
  const int j    = tid & 127;
  const int tg   = j >> 3;
  const int dg   = j & 7;
  const u16* src = half ? Vb : Kb;
  u16* dst = half ? sVT : sKT;
  const int colb = (4 * tg + 8 * dg) & 63;

  const size_t rowBase = (size_t)b * 4096 + (size_t)chunk * 256;
  const size_t gbase = (rowBase + 4 * tg) * 1024 + (size_t)h * 64 + dg * 8;

  u16x8v pre[2][4];
#pragma unroll
  for (int s = 0; s < 4; s++)
    pre[0][s] = *(const u16x8v*)(src + gbase + (size_t)s * 1024);

#pragma unroll
  for (int st = 0; st < 4; st++) {
    const int cb = st & 1;
    __syncthreads();
#pragma unroll
    for (int e = 0; e < 8; e++) {
      u16x4 w;
      w[0] = pre[cb][0][e]; w[1] = pre[cb][1][e];
      w[2] = pre[cb][2][e]; w[3] = pre[cb][3][e];
      *(u16x4*)&dst[(dg * 8 + e) * 64 + colb] = w;
    }
    if (st + 1 < 4) {
      const size_t nb = gbase + (size_t)(st + 1) * 64 * 1024;
#pragma unroll
      for (int s = 0; s < 4; s++)
        pre[cb ^ 1][s] = *(const u16x8v*)(src + nb + (size_t)s * 1024);
    }
    __syncthreads();

#pragma unroll
    for (int kst = 0; kst < 2; kst++) {
      const int q8 = kst * 32 + (lane >> 4) * 8;
      bf16x8 bfrag;
      {
        const int rr = wave * 16 + (lane & 15);
        const int c = (q8 + 8 * (rr >> 3)) & 63;
        bfrag = *(const bf16x8*)&sVT[rr * 64 + c];
      }
#pragma unroll
      for (int i = 0; i < 4; i++) {
        const int rr = i * 16 + (lane & 15);
        const int c = (q8 + 8 * (rr >> 3)) & 63;
        const bf16x8 afrag = *(const bf16x8*)&sKT[rr * 64 + c];
        acc[i] = __builtin_amdgcn_mfma_f32_16x16x32_bf16(afrag, bfrag, acc[i], 0, 0, 0);
        if (wave == 0)
          accs[i] = __builtin_amdgcn_mfma_f32_16x16x32_bf16(afrag, ones, accs[i], 0, 0, 0);
      }
    }
  }

  const int r0 = (lane >> 4) * 4, cc = lane & 15;
  float* kvp = kv_part + ((size_t)chunk * 64 + bh) * 4096;
#pragma unroll
  for (int i = 0; i < 4; i++)
#pragma unroll
    for (int jj = 0; jj < 4; jj++)
      kvp[(size_t)(i * 16 + r0 + jj) * 64 + wave * 16 + cc] = acc[i][jj];
  if (wave == 0 && cc == 0) {
#pragma unroll
    for (int i = 0; i < 4; i++)
#pragma unroll
      for (int jj = 0; jj < 4; jj++)
        ksum_part[((size_t)chunk * 64 + bh) * 64 + i * 16 + r0 + jj] = accs[i][jj];
  }
}

// ---------- reduce 16 kv partials -> TRANSPOSED bf16 kvbfT [bh][m][d] ----------
// LDS transpose (padded [64][65] f32, conflict-free) so kvbfT writes are
// vectorized 16B and attn_apply can stage kv with u16x8 loads.
__global__ __launch_bounds__(256) void kv_reduce_kernel(
    const float* __restrict__ kv_part, const float* __restrict__ ksum_part,
    u16* __restrict__ kvbfT, float* __restrict__ ksum) {
  const int bh = blockIdx.x;
  const int tid = threadIdx.x;
  __shared__ float sfull[64][65];
#pragma unroll
  for (int it = 0; it < 4; it++) {
    const int idx = it * 1024 + tid * 4;      // d = idx>>6, m0 = idx&63
    float4 s = {0.f, 0.f, 0.f, 0.f};
#pragma unroll
    for (int c = 0; c < 16; c++) {
      const float4 p = *(const float4*)&kv_part[((size_t)c * 64 + bh) * 4096 + idx];
      s.x += p.x; s.y += p.y; s.z += p.z; s.w += p.w;
    }
    const int d = idx >> 6, m0 = idx & 63;
    sfull[d][m0] = s.x; sfull[d][m0 + 1] = s.y;
    sfull[d][m0 + 2] = s.z; sfull[d][m0 + 3] = s.w;
  }
  __syncthreads();
  {
    const int m = tid >> 2, dq = (tid & 3) * 16;
    u16x8v o0, o1;
#pragma unroll
    for (int e = 0; e < 8; e++) {
      o0[e] = f2bf(sfull[dq + e][m]);
      o1[e] = f2bf(sfull[dq + 8 + e][m]);
    }
    *(u16x8v*)&kvbfT[(size_t)bh * 4096 + m * 64 + dq]     = o0;
    *(u16x8v*)&kvbfT[(size_t)bh * 4096 + m * 64 + dq + 8] = o1;
  }
  if (tid < 64) {
    float s = 0.f;
#pragma unroll
    for (int c = 0; c < 16; c++)
      s += ksum_part[((size_t)c * 64 + bh) * 64 + tid];
    ksum[(size_t)bh * 64 + tid] = s;
  }
}

// ---------- attn[t, h*64+m] = (Q[t,:] @ kv) * z[t], 4 row-subtiles/block ----------
// All staging vectorized: u16x8 (16B/lane) for Q and kvbfT (was scalar u16 —
// Common-mistake #2, ~2x on 64MB of traffic).
#define QST 80
__global__ __launch_bounds__(256) void attn_apply_kernel(
    const u16* __restrict__ Qb, const u16* __restrict__ kvbfT,
    const float* __restrict__ ksum, u16* __restrict__ attn) {
  const int bh = blockIdx.y;
  const int t4 = blockIdx.x;           // 16 blocks x 256 rows
  const int b = bh >> 4, h = bh & 15;
  const int tid = threadIdx.x, wave = tid >> 6, lane = tid & 63;

  __shared__ u16 skvT[64 * QST];   // [m][d]  (staged ONCE per block)
  __shared__ u16 sq[64 * QST];     // [t][d]  (per sub-tile)
  __shared__ float sz[64];
  __shared__ float sks[64];
  __shared__ float szp[256];

  if (tid < 64) sks[tid] = ksum[(size_t)bh * 64 + tid] + EPS;
  const u16* kvp = kvbfT + (size_t)bh * 4096;    // [m][d]
  for (int i = tid; i < 512; i += 256) {
    const int mm = i >> 3, d8 = (i & 7) * 8;
    *(u16x8v*)&skvT[mm * QST + d8] = *(const u16x8v*)&kvp[mm * 64 + d8];
  }

  const size_t qbase0 = ((size_t)b * 4096 + (size_t)t4 * 256) * 1024 + h * 64;

  for (int st = 0; st < 4; ++st) {
    const size_t qbase = qbase0 + (size_t)st * 64 * 1024;
    __syncthreads();   // st=0: skvT/sks ready; st>0: prev sq reads retired (WAR)
    for (int i = tid; i < 512; i += 256) {
      const int r = i >> 3, d8 = (i & 7) * 8;
      *(u16x8v*)&sq[r * QST + d8] =
          *(const u16x8v*)&Qb[qbase + (size_t)r * 1024 + d8];
    }
    __syncthreads();

    // parallel z: 64 rows x 4 groups of 16-d partials, LDS reduce
    {
      const int zr = tid & 63, zg = tid >> 6;
      float pz = 0.f;
#pragma unroll
      for (int jj = 0; jj < 16; jj++) {
        const int dd = zg * 16 + jj;
        pz += bf2f(sq[zr * QST + dd]) * sks[dd];
      }
      szp[zg * 64 + zr] = pz;
    }
    __syncthreads();
    if (tid < 64)
      sz[tid] = 1.f / (szp[tid] + szp[64 + tid] + szp[128 + tid] + szp[192 + tid] + EPS);
    __syncthreads();

    f32x4 acc[4] = {};
#pragma unroll
    for (int ks2 = 0; ks2 < 2; ks2++) {
      const bf16x8 a = *(const bf16x8*)&sq[(wave * 16 + (lane & 15)) * QST + ks2 * 32 + (lane >> 4) * 8];
#pragma unroll
      for (int ni = 0; ni < 4; ni++) {
        const bf16x8 bv = *(const bf16x8*)&skvT[(ni * 16 + (lane & 15)) * QST + ks2 * 32 + (lane >> 4) * 8];
        acc[ni] = __builtin_amdgcn_mfma_f32_16x16x32_bf16(a, bv, acc[ni], 0, 0, 0);
      }
    }

    const int r0 = (lane >> 4) * 4, cc = lane & 15;
#pragma unroll
    for (int ni = 0; ni < 4; ni++) {
#pragma unroll
      for (int j = 0; j < 4; j++) {
        const int r = wave * 16 + r0 + j;
        const int c = ni * 16 + cc;
        const float val = acc[ni][j] * sz[r];
        attn[qbase + (size_t)r * 1024 + c] = f2bf(val);
      }
    }
  }
}

// ---------- launch ----------
extern "C" void kernel_launch(void* const* d_in, const int* in_sizes, int n_in,
                              void* d_out, int out_size, void* d_ws, size_t ws_size,
                              hipStream_t stream) {
  (void)in_sizes; (void)n_in; (void)out_size; (void)ws_size;
  const float* x  = (const float*)d_in[0];
  const float* Wq = (const float*)d_in[1];
  const float* bq = (const float*)d_in[2];
  const float* Wk = (const float*)d_in[3];
  const float* bk = (const float*)d_in[4];
  const float* Wv = (const float*)d_in[5];
  const float* bv = (const float*)d_in[6];
  const float* Wo = (const float*)d_in[7];
  const float* bo = (const float*)d_in[8];

  // B=4, T=4096, D=1024, H=16, DK=64; M = B*T = 16384
  char* ws = (char*)d_ws;
  u16* xb    = (u16*)ws;  ws += 33554432;              // [16384,1024] bf16
  u16* wqkvb = (u16*)ws;  ws += 6291456;               // [3072,1024] bf16 (Q|K|V)
  u16* wob   = (u16*)ws;  ws += 2097152;
  u16* Vb    = (u16*)ws;  ws += 33554432;
  u16* attn  = (u16*)ws;  ws += 33554432;
  float* ksum_part = (float*)ws; ws += 262144;         // [16][64][64] fp32
  u16*   kvbfT     = (u16*)ws;   ws += 524288;         // [64][64][64] bf16 [m][d]
  float* ksum      = (float*)ws; ws += 16384;          // [64][64] fp32

  // kv_part [16][64][64][64] fp32 = 16MB ALIASED onto attn (32MB): dead
  // after kv_reduce, before attn_apply writes attn (stream-ordered).
  float* kv_part = (float*)attn;

  u16* Qb = (u16*)d_out;
  u16* Kb = Qb + 16777216;

  cvt_all_kernel<<<10240, 256, 0, stream>>>(x, Wq, Wk, Wv, Wo,
                                            xb, wqkvb, wqkvb + 1048576,
                                            wqkvb + 2097152, wob);

  // fused QKV GEMM: [16384,1024] x [3072,1024]^T, N=3072
  gemm4r<1><<<dim3(64, 12), 512, 0, stream>>>(
      xb, wqkvb, bq, bk, bv, Qb, Kb, Vb, nullptr, 1024);

  kv_mfma_kernel<<<dim3(16, 64), dim3(256), 0, stream>>>(Kb, Vb, kv_part, ksum_part);
  kv_reduce_kernel<<<64, 256, 0, stream>>>(kv_part, ksum_part, kvbfT, ksum);
  attn_apply_kernel<<<dim3(16, 64), dim3(256), 0, stream>>>(Qb, kvbfT, ksum, attn);

  // output GEMM: [16384,1024] x [1024,1024]^T -> fp32
  gemm4r<0><<<dim3(64, 4), 512, 0, stream>>>(
      attn, wob, bo, nullptr, nullptr, nullptr, nullptr, nullptr,
      (float*)d_out, 1024);
}